// Round 15
// baseline (1119.172 us; speedup 1.0000x reference)
//
#include <hip/hip_runtime.h>
#include <hip/hip_bf16.h>
#include <cmath>

typedef __attribute__((ext_vector_type(8)))  __bf16 bf16x8;
typedef __attribute__((ext_vector_type(4)))  float  f32x4;
typedef __attribute__((ext_vector_type(16))) float  f32x16;
typedef const __attribute__((address_space(1))) void* as1cv;
typedef __attribute__((address_space(3))) void*       as3v;

static constexpr int BB = 8, TT = 16, NN = 65, LD = 256, HD = 512, NH = 8, NL = 6;
static constexpr int SS    = TT * (NN + 1);   // 1056
static constexpr int ROWS  = BB * SS;         // 8448
static constexpr int PROWS = BB * TT * NN;    // 8320
static constexpr int MLPD  = 2048;

// ---------- transpose + cast: f32 (R,C) -> bf16 (C,R), batched ----------
__global__ void transpose_cast(const float* __restrict__ in, __bf16* __restrict__ out,
                               int R, int C, size_t ibs, size_t obs)
{
  __shared__ float t[32][33];
  in  += ibs * blockIdx.z;
  out += obs * blockIdx.z;
  int bx = blockIdx.x * 32, by = blockIdx.y * 32;
  #pragma unroll
  for (int i = threadIdx.y; i < 32; i += 8)
    t[i][threadIdx.x] = in[(size_t)(by + i) * C + bx + threadIdx.x];
  __syncthreads();
  #pragma unroll
  for (int i = threadIdx.y; i < 32; i += 8)
    out[(size_t)(bx + i) * R + by + threadIdx.x] = (__bf16)t[threadIdx.x][i];
}

// ---------- straight f32 -> bf16 cast (8 elems/thread) ----------
__global__ __launch_bounds__(256) void cast_bf16(const float* __restrict__ in,
                                                 __bf16* __restrict__ out)
{
  int i = (blockIdx.x * 256 + threadIdx.x) * 8;
  float4 a = *(const float4*)(in + i);
  float4 b = *(const float4*)(in + i + 4);
  bf16x8 o;
  o[0]=(__bf16)a.x; o[1]=(__bf16)a.y; o[2]=(__bf16)a.z; o[3]=(__bf16)a.w;
  o[4]=(__bf16)b.x; o[5]=(__bf16)b.y; o[6]=(__bf16)b.z; o[7]=(__bf16)b.w;
  *(bf16x8*)(out + i) = o;
}

// ---------- concat q/k/v biases into (NL,1536) ----------
__global__ void build_bqkv(const float* __restrict__ bq, const float* __restrict__ bk,
                           const float* __restrict__ bv, float* __restrict__ out)
{
  int i = blockIdx.x * 256 + threadIdx.x;      // 0..9215
  int L = i / 1536, c = i % 1536;
  float v = (c < 512) ? bq[L*512 + c] : (c < 1024 ? bk[L*512 + c - 512] : bv[L*512 + c - 1024]);
  out[i] = v;
}

// ---------- GEMM: BM=64 x BN=256, wave-tile 64x64 (LDS-reuse-max; QKV / MLP-up) ----------
// 4 waves side-by-side in N. Per K-step/wave: 16 ds_read_b128 vs 32 MFMA -> MFMA-bound.
// FLAGS: 1=GELU  4=bf16 out  8=f32 out  32=QKV split (qk packed, v transposed)
template<int FLAGS>
__global__ __launch_bounds__(256)
void gemm_w64(const __bf16* __restrict__ A, const __bf16* __restrict__ Bt,
              const float* __restrict__ bias,
              float* __restrict__ outF, __bf16* __restrict__ outB, __bf16* __restrict__ outB2,
              int M, int N, int K)
{
  __shared__ __bf16 As[64 * 64];
  __shared__ __bf16 Bs[256 * 64];
  const int tid = threadIdx.x;
  const int lane = tid & 63, w = tid >> 6;
  const int g = lane >> 4, cl = lane & 15;
  const int gx = gridDim.x, nwg = gx * gridDim.y;
  const int orig = blockIdx.y * gx + blockIdx.x;
  const int q8 = nwg >> 3, r8 = nwg & 7;
  const int xcd = orig & 7, off = orig >> 3;
  const int tile = (xcd < r8 ? xcd * (q8 + 1) : r8 * (q8 + 1) + (xcd - r8) * q8) + off;
  const int tm = (tile / gx) * 64, tn = (tile % gx) * 256;

  f32x4 acc[4][4];
  const f32x4 zero4 = {0.f, 0.f, 0.f, 0.f};
  #pragma unroll
  for (int m = 0; m < 4; m++)
    #pragma unroll
    for (int n = 0; n < 4; n++) acc[m][n] = zero4;

  const int nk = K >> 6;
  for (int kt = 0; kt < nk; ++kt) {
    __syncthreads();
    const __bf16* Ag = A  + (size_t)tm * K + kt * 64;
    const __bf16* Bg = Bt + (size_t)tn * K + kt * 64;
    #pragma unroll
    for (int p = 0; p < 2; p++) {                 // A: 64x64 = 512 chunks
      int c = p * 256 + tid;
      int row = c >> 3, j = c & 7;
      int jj = j ^ (row & 7);
      const __bf16* sa = Ag + (size_t)row * K + jj * 8;
      __builtin_amdgcn_global_load_lds((as1cv)sa, (as3v)&As[(p * 4 + w) * 512], 16, 0, 0);
    }
    #pragma unroll
    for (int p = 0; p < 8; p++) {                 // B: 256x64 = 2048 chunks
      int c = p * 256 + tid;
      int row = c >> 3, j = c & 7;
      int jj = j ^ (row & 7);
      const __bf16* sb = Bg + (size_t)row * K + jj * 8;
      __builtin_amdgcn_global_load_lds((as1cv)sb, (as3v)&Bs[(p * 4 + w) * 512], 16, 0, 0);
    }
    __syncthreads();
    #pragma unroll
    for (int kk = 0; kk < 2; kk++) {
      bf16x8 af[4], bfr[4];
      #pragma unroll
      for (int m = 0; m < 4; m++) {
        int row = m * 16 + cl;
        af[m] = *(const bf16x8*)&As[row * 64 + ((kk * 4 + g) ^ (row & 7)) * 8];
      }
      #pragma unroll
      for (int n = 0; n < 4; n++) {
        int row = w * 64 + n * 16 + cl;
        bfr[n] = *(const bf16x8*)&Bs[row * 64 + ((kk * 4 + g) ^ (row & 7)) * 8];
      }
      #pragma unroll
      for (int m = 0; m < 4; m++)
        #pragma unroll
        for (int n = 0; n < 4; n++)
          acc[m][n] = __builtin_amdgcn_mfma_f32_16x16x32_bf16(af[m], bfr[n], acc[m][n], 0, 0, 0);
    }
  }
  float bv[4];
  #pragma unroll
  for (int n = 0; n < 4; n++) bv[n] = bias[tn + w * 64 + n * 16 + cl];
  #pragma unroll
  for (int m = 0; m < 4; m++) {
    int Rb = tm + m * 16 + g * 4;
    #pragma unroll
    for (int i = 0; i < 4; i++) {
      int R = Rb + i;
      #pragma unroll
      for (int n = 0; n < 4; n++) {
        int C = tn + w * 64 + n * 16 + cl;
        float v = acc[m][n][i] + bv[n];
        if (FLAGS & 1) v = 0.5f * v * (1.f + erff(v * 0.70710678118f));
        if (FLAGS & 8) outF[(size_t)R * N + C] = v;
        if (FLAGS & 4) outB[(size_t)R * N + C] = (__bf16)v;
        if (FLAGS & 32) {
          if (C < 1024) {
            outB[(size_t)R * 1024 + C] = (__bf16)v;           // q|k packed, stride 1024
          } else {
            int bb2 = R / SS, s2 = R % SS;
            int cc = C - 1024, hh = cc >> 6, dd = cc & 63;
            outB2[((size_t)((bb2 * NH + hh) * 64 + dd)) * SS + s2] = (__bf16)v;  // V^T
          }
        }
      }
    }
  }
}

// ---------- GEMM: BM=64 x BN=64 (occupancy-max, small-N GEMMs) ----------
// FLAGS: 1=GELU 2=+resid 4=bf16 8=f32 64=fused final add (out = z + sigmoid(rw)*v, patch scatter)
template<int FLAGS>
__global__ __launch_bounds__(256)
void gemm_n64(const __bf16* __restrict__ A, const __bf16* __restrict__ Bt,
              const float* __restrict__ bias, const float* __restrict__ resid,
              float* __restrict__ outF, __bf16* __restrict__ outB,
              int M, int N, int K,
              const float* __restrict__ zf, const float* __restrict__ rwp)
{
  __shared__ __bf16 As[64 * 64];
  __shared__ __bf16 Bs[64 * 64];
  const int tid = threadIdx.x;
  const int lane = tid & 63, w = tid >> 6;
  const int g = lane >> 4, cl = lane & 15;
  const int wr = w >> 1, wc = w & 1;
  const int gx = gridDim.x, nwg = gx * gridDim.y;
  const int orig = blockIdx.y * gx + blockIdx.x;
  const int q8 = nwg >> 3, r8 = nwg & 7;
  const int xcd = orig & 7, off = orig >> 3;
  const int tile = (xcd < r8 ? xcd * (q8 + 1) : r8 * (q8 + 1) + (xcd - r8) * q8) + off;
  const int tm = (tile / gx) * 64, tn = (tile % gx) * 64;

  f32x4 acc[2][2];
  const f32x4 zero4 = {0.f, 0.f, 0.f, 0.f};
  #pragma unroll
  for (int m = 0; m < 2; m++)
    #pragma unroll
    for (int n = 0; n < 2; n++) acc[m][n] = zero4;

  const int nk = K >> 6;
  for (int kt = 0; kt < nk; ++kt) {
    __syncthreads();
    const __bf16* Ag = A  + (size_t)tm * K + kt * 64;
    const __bf16* Bg = Bt + (size_t)tn * K + kt * 64;
    #pragma unroll
    for (int p = 0; p < 2; p++) {
      int c = p * 256 + tid;
      int row = c >> 3, j = c & 7;
      int jj = j ^ (row & 7);
      const __bf16* sa = Ag + (size_t)row * K + jj * 8;
      const __bf16* sb = Bg + (size_t)row * K + jj * 8;
      __builtin_amdgcn_global_load_lds((as1cv)sa, (as3v)&As[(p * 4 + w) * 512], 16, 0, 0);
      __builtin_amdgcn_global_load_lds((as1cv)sb, (as3v)&Bs[(p * 4 + w) * 512], 16, 0, 0);
    }
    __syncthreads();
    #pragma unroll
    for (int kk = 0; kk < 2; kk++) {
      bf16x8 af[2], bfr[2];
      #pragma unroll
      for (int m = 0; m < 2; m++) {
        int row = wr * 32 + m * 16 + cl;
        af[m] = *(const bf16x8*)&As[row * 64 + ((kk * 4 + g) ^ (row & 7)) * 8];
      }
      #pragma unroll
      for (int n = 0; n < 2; n++) {
        int row = wc * 32 + n * 16 + cl;
        bfr[n] = *(const bf16x8*)&Bs[row * 64 + ((kk * 4 + g) ^ (row & 7)) * 8];
      }
      #pragma unroll
      for (int m = 0; m < 2; m++)
        #pragma unroll
        for (int n = 0; n < 2; n++)
          acc[m][n] = __builtin_amdgcn_mfma_f32_16x16x32_bf16(af[m], bfr[n], acc[m][n], 0, 0, 0);
    }
  }
  const float alphaF = (FLAGS & 64) ? 1.f / (1.f + __expf(-rwp[0])) : 0.f;
  float bv[2];
  #pragma unroll
  for (int n = 0; n < 2; n++) bv[n] = bias[tn + wc * 32 + n * 16 + cl];
  #pragma unroll
  for (int m = 0; m < 2; m++) {
    int Rb = tm + wr * 32 + m * 16 + g * 4;
    #pragma unroll
    for (int i = 0; i < 4; i++) {
      int R = Rb + i;
      #pragma unroll
      for (int n = 0; n < 2; n++) {
        int C = tn + wc * 32 + n * 16 + cl;
        float v = acc[m][n][i] + bv[n];
        if (FLAGS & 1) v = 0.5f * v * (1.f + erff(v * 0.70710678118f));
        if (FLAGS & 2) v += resid[(size_t)R * N + C];
        if (FLAGS & 8) outF[(size_t)R * N + C] = v;
        if (FLAGS & 4) outB[(size_t)R * N + C] = (__bf16)v;
        if (FLAGS & 64) {
          int bb2 = R / SS, s2 = R % SS;
          int t = s2 / 66, k = s2 % 66;
          if (k > 0) {
            size_t oi = ((size_t)((bb2 * TT + t) * NN + (k - 1))) * LD + C;
            outF[oi] = zf[oi] + alphaF * v;
          }
        }
      }
    }
  }
}

// ---------- LayerNorm: f32 in -> bf16 out, 1 wave per 512-col row ----------
__global__ __launch_bounds__(256) void ln_bf16(const float* __restrict__ in,
    const float* __restrict__ gam, const float* __restrict__ bet, __bf16* __restrict__ out)
{
  int w = threadIdx.x >> 6, l = threadIdx.x & 63;
  size_t row = (size_t)blockIdx.x * 4 + w;
  const float4* x4 = (const float4*)(in + row * HD);
  float4 v0 = x4[l], v1 = x4[l + 64];
  float s  = v0.x + v0.y + v0.z + v0.w + v1.x + v1.y + v1.z + v1.w;
  float q2 = v0.x*v0.x + v0.y*v0.y + v0.z*v0.z + v0.w*v0.w
           + v1.x*v1.x + v1.y*v1.y + v1.z*v1.z + v1.w*v1.w;
  #pragma unroll
  for (int m = 1; m < 64; m <<= 1) { s += __shfl_xor(s, m); q2 += __shfl_xor(q2, m); }
  float mean = s * (1.f / HD);
  float rstd = rsqrtf(q2 * (1.f / HD) - mean * mean + 1e-5f);
  int c0 = l * 4, c1 = 256 + l * 4;
  float4 g0 = *(const float4*)(gam + c0), g1 = *(const float4*)(gam + c1);
  float4 e0 = *(const float4*)(bet + c0), e1 = *(const float4*)(bet + c1);
  __bf16* o = out + row * HD;
  o[c0+0] = (__bf16)((v0.x-mean)*rstd*g0.x + e0.x);
  o[c0+1] = (__bf16)((v0.y-mean)*rstd*g0.y + e0.y);
  o[c0+2] = (__bf16)((v0.z-mean)*rstd*g0.z + e0.z);
  o[c0+3] = (__bf16)((v0.w-mean)*rstd*g0.w + e0.w);
  o[c1+0] = (__bf16)((v1.x-mean)*rstd*g1.x + e1.x);
  o[c1+1] = (__bf16)((v1.y-mean)*rstd*g1.y + e1.y);
  o[c1+2] = (__bf16)((v1.z-mean)*rstd*g1.z + e1.z);
  o[c1+3] = (__bf16)((v1.w-mean)*rstd*g1.w + e1.w);
}

// ---------- action-token embedding ----------
__global__ __launch_bounds__(64) void act_embed(const float* __restrict__ cont,
    const int* __restrict__ disc, const float* __restrict__ w_de,
    const float* __restrict__ w_cp, const float* __restrict__ b_cp,
    const float* __restrict__ w_ap, const float* __restrict__ b_ap,
    const float* __restrict__ w_te, float* __restrict__ x)
{
  int t = blockIdx.x, b = blockIdx.y, l = threadIdx.x;
  int da = disc[b * TT + t];
  float c0 = cont[(b * TT + t) * 2], c1 = cont[(b * TT + t) * 2 + 1];
  int c = l * 8;
  float accv[8];
  #pragma unroll
  for (int j = 0; j < 8; j++) accv[j] = b_ap[c + j];
  for (int i = 0; i < 64; i++) {
    float ai = w_de[da * 64 + i];
    #pragma unroll
    for (int j = 0; j < 8; j++) accv[j] += ai * w_ap[i * HD + c + j];
  }
  for (int i = 0; i < 64; i++) {
    float ce = c0 * w_cp[i] + c1 * w_cp[64 + i] + b_cp[i];
    #pragma unroll
    for (int j = 0; j < 8; j++) accv[j] += ce * w_ap[(64 + i) * HD + c + j];
  }
  #pragma unroll
  for (int j = 0; j < 8; j++)
    x[((size_t)(b * SS) + t * 66) * HD + c + j] = accv[j] + w_te[t * HD + c + j];
}

// ---------- scatter patch tokens ----------
__global__ __launch_bounds__(256) void assemble_patch(const float* __restrict__ pt,
    const float* __restrict__ te, float* __restrict__ x)
{
  int idx = (blockIdx.x * 256 + threadIdx.x) * 4;
  int c = idx & (HD - 1);
  int r = idx >> 9;
  int n = r % NN; int bt = r / NN; int t = bt & (TT - 1); int bb = bt >> 4;
  float4 v  = *(const float4*)(pt + idx);
  float4 tv = *(const float4*)(te + t * HD + c);
  v.x += tv.x; v.y += tv.y; v.z += tv.z; v.w += tv.w;
  *(float4*)(x + ((size_t)(bb * SS + t * 66 + 1 + n)) * HD + c) = v;
}

__device__ inline unsigned pkbf(float lo, float hi2) {
  unsigned short a = __builtin_bit_cast(unsigned short, (__bf16)lo);
  unsigned short b = __builtin_bit_cast(unsigned short, (__bf16)hi2);
  return (unsigned)a | ((unsigned)b << 16);
}

// ---------- flash attention v10: v9 + heavy-jobs-first ordering (tail reduction) ----------
// qt = 32 - (rem % 33): longest kv-range jobs dispatch first within each XCD.
__global__ __launch_bounds__(256) void attn_fwd(const __bf16* __restrict__ qk,
    const __bf16* __restrict__ vT, __bf16* __restrict__ o)
{
  const int w = threadIdx.x >> 6, lane = threadIdx.x & 63;
  const int lin = (blockIdx.x & 7) * 264 + (blockIdx.x >> 3);  // bijective, 2112 blocks
  const int b   = lin / 264;                                   // == blockIdx.x & 7 (XCD)
  const int rem = lin % 264;
  const int h = rem / 33, qt = 32 - (rem % 33);
  const int l31 = lane & 31, hi = lane >> 5;
  const int q = qt * 32 + l31;
  const int kend = (q / 66 + 1) * 66;
  const int nkv = (((qt * 32 + 31) / 66 + 1) * 66 + 31) >> 5;
  const float SCL = 0.125f * 1.44269504f;    // log2e folded (exp2 domain)

  __shared__ float red[4][32];
  __shared__ float lmS[4][32], llS[4][32];
  __shared__ float laS[3][64][33];           // +1 pad: conflict-free merge
  __shared__ float red2[32][9];              // +1 pad

  bf16x8 qf[4];
  const __bf16* qbase = qk + (size_t)(b * SS + q) * 1024 + h * 64 + hi * 8;
  #pragma unroll
  for (int s = 0; s < 4; s++) qf[s] = *(const bf16x8*)(qbase + s * 16);

  const f32x16 z16 = {0,0,0,0,0,0,0,0,0,0,0,0,0,0,0,0};
  f32x16 accA = z16, accB = z16;
  float m = -1e30f, lsum = 0.f;

  for (int kb = w; kb < nkv; kb += 4) {
    const int K0 = kb * 32;
    const __bf16* kbase = qk + (size_t)(b * SS + K0 + l31) * 1024 + 512 + h * 64 + hi * 8;
    bf16x8 kf0 = *(const bf16x8*)(kbase);
    bf16x8 kf1 = *(const bf16x8*)(kbase + 16);
    bf16x8 kf2 = *(const bf16x8*)(kbase + 32);
    bf16x8 kf3 = *(const bf16x8*)(kbase + 48);
    const __bf16* vbase = vT + (size_t)((b * NH + h) * 64 + l31) * SS + K0 + hi * 8;
    bf16x8 vf00 = *(const bf16x8*)(vbase);
    bf16x8 vf10 = *(const bf16x8*)(vbase + 16);
    bf16x8 vf01 = *(const bf16x8*)(vbase + (size_t)32 * SS);
    bf16x8 vf11 = *(const bf16x8*)(vbase + (size_t)32 * SS + 16);

    f32x16 st = z16;
    st = __builtin_amdgcn_mfma_f32_32x32x16_bf16(kf0, qf[0], st, 0, 0, 0);
    st = __builtin_amdgcn_mfma_f32_32x32x16_bf16(kf1, qf[1], st, 0, 0, 0);
    st = __builtin_amdgcn_mfma_f32_32x32x16_bf16(kf2, qf[2], st, 0, 0, 0);
    st = __builtin_amdgcn_mfma_f32_32x32x16_bf16(kf3, qf[3], st, 0, 0, 0);

    float p[16];
    #pragma unroll
    for (int r = 0; r < 16; r++) {
      int kg = K0 + (r & 3) + 8 * (r >> 2) + 4 * hi;
      p[r] = (kg < kend) ? st[r] * SCL : -1e30f;
    }
    float mx = fmaxf(fmaxf(fmaxf(p[0],p[1]),fmaxf(p[2],p[3])),
                     fmaxf(fmaxf(p[4],p[5]),fmaxf(p[6],p[7])));
    mx = fmaxf(mx, fmaxf(fmaxf(fmaxf(p[8],p[9]),fmaxf(p[10],p[11])),
                         fmaxf(fmaxf(p[12],p[13]),fmaxf(p[14],p[15]))));
    mx = fmaxf(mx, __shfl_xor(mx, 32));
    if (__any(mx > m + 11.5416f)) {          // defer-max, e^8 bound (log2)
      float nm = fmaxf(m, mx);
      float alp = exp2f(m - nm);
      m = nm; lsum *= alp;
      if (lane < 32) red[w][lane] = alp;
      asm volatile("s_waitcnt lgkmcnt(0)" ::: "memory");
      float4 a0 = *(const float4*)&red[w][hi * 4];
      float4 a1 = *(const float4*)&red[w][hi * 4 + 8];
      float4 a2 = *(const float4*)&red[w][hi * 4 + 16];
      float4 a3 = *(const float4*)&red[w][hi * 4 + 24];
      float afv[16] = {a0.x,a0.y,a0.z,a0.w, a1.x,a1.y,a1.z,a1.w,
                       a2.x,a2.y,a2.z,a2.w, a3.x,a3.y,a3.z,a3.w};
      #pragma unroll
      for (int r = 0; r < 16; r++) { accA[r] *= afv[r]; accB[r] *= afv[r]; }
    }
    float rs;
    #pragma unroll
    for (int r = 0; r < 16; r++) p[r] = exp2f(p[r] - m);
    rs = ((p[0]+p[1])+(p[2]+p[3])) + ((p[4]+p[5])+(p[6]+p[7]))
       + ((p[8]+p[9])+(p[10]+p[11])) + ((p[12]+p[13])+(p[14]+p[15]));
    rs += __shfl_xor(rs, 32);
    lsum += rs;
    unsigned a0p = pkbf(p[0], p[1]),  a1p = pkbf(p[2], p[3]);
    unsigned a2p = pkbf(p[4], p[5]),  a3p = pkbf(p[6], p[7]);
    unsigned b0p = pkbf(p[8], p[9]),  b1p = pkbf(p[10], p[11]);
    unsigned b2p = pkbf(p[12], p[13]), b3p = pkbf(p[14], p[15]);
    unsigned s0 = __shfl_xor(a0p, 32), s1 = __shfl_xor(a1p, 32);
    unsigned s2 = __shfl_xor(a2p, 32), s3 = __shfl_xor(a3p, 32);
    unsigned t0 = __shfl_xor(b0p, 32), t1 = __shfl_xor(b1p, 32);
    unsigned t2 = __shfl_xor(b2p, 32), t3 = __shfl_xor(b3p, 32);
    union { unsigned u[4]; bf16x8 v; } af0, af1;
    af0.u[0] = hi ? s2 : a0p;  af0.u[1] = hi ? s3 : a1p;
    af0.u[2] = hi ? a2p : s0;  af0.u[3] = hi ? a3p : s1;
    af1.u[0] = hi ? t2 : b0p;  af1.u[1] = hi ? t3 : b1p;
    af1.u[2] = hi ? b2p : t0;  af1.u[3] = hi ? b3p : t1;
    accA = __builtin_amdgcn_mfma_f32_32x32x16_bf16(af0.v, vf00, accA, 0, 0, 0);
    accA = __builtin_amdgcn_mfma_f32_32x32x16_bf16(af1.v, vf10, accA, 0, 0, 0);
    accB = __builtin_amdgcn_mfma_f32_32x32x16_bf16(af0.v, vf01, accB, 0, 0, 0);
    accB = __builtin_amdgcn_mfma_f32_32x32x16_bf16(af1.v, vf11, accB, 0, 0, 0);
  }

  // ---- split-K merge: O = sum_w O_w 2^{m_w-M}; L = sum_w l_w 2^{m_w-M} ----
  if (lane < 32) { lmS[w][lane] = m; llS[w][lane] = lsum; }
  if (w > 0) {
    #pragma unroll
    for (int r = 0; r < 16; r++) {
      laS[w - 1][lane][r]      = accA[r];
      laS[w - 1][lane][16 + r] = accB[r];
    }
  }
  __syncthreads();
  if (w != 0) return;
  float m0 = lmS[0][l31], m1 = lmS[1][l31], m2 = lmS[2][l31], m3 = lmS[3][l31];
  float M = fmaxf(fmaxf(m0, m1), fmaxf(m2, m3));
  float f0 = exp2f(m0 - M), f1 = exp2f(m1 - M);
  float f2 = exp2f(m2 - M), f3 = exp2f(m3 - M);
  float L = llS[0][l31] * f0 + llS[1][l31] * f1 + llS[2][l31] * f2 + llS[3][l31] * f3;
  if (lane < 32) {
    red2[lane][0] = f0; red2[lane][1] = f1;
    red2[lane][2] = f2; red2[lane][3] = f3;
    red2[lane][4] = 1.f / L;
  }
  asm volatile("s_waitcnt lgkmcnt(0)" ::: "memory");
  __bf16* obase = o + (size_t)(b * SS + qt * 32) * HD + h * 64 + l31;
  #pragma unroll
  for (int r = 0; r < 16; r++) {
    int qr = (r & 3) + 8 * (r >> 2) + 4 * hi;
    float4 fv = *(const float4*)&red2[qr][0];
    float il = red2[qr][4];
    float oa = (accA[r] * fv.x + laS[0][lane][r] * fv.y
              + laS[1][lane][r] * fv.z + laS[2][lane][r] * fv.w) * il;
    float ob = (accB[r] * fv.x + laS[0][lane][16 + r] * fv.y
              + laS[1][lane][16 + r] * fv.z + laS[2][lane][16 + r] * fv.w) * il;
    obase[(size_t)qr * HD]      = (__bf16)oa;
    obase[(size_t)qr * HD + 32] = (__bf16)ob;
  }
}

extern "C" void kernel_launch(void* const* d_in, const int* in_sizes, int n_in,
                              void* d_out, int out_size, void* d_ws, size_t ws_size,
                              hipStream_t stream)
{
  const float* z    = (const float*)d_in[0];
  const float* cont = (const float*)d_in[1];
  const int*   disc = (const int*)d_in[2];
  const float* w_de = (const float*)d_in[3];
  const float* w_cp = (const float*)d_in[4];
  const float* b_cp = (const float*)d_in[5];
  const float* w_ap = (const float*)d_in[6];
  const float* b_ap = (const float*)d_in[7];
  const float* w_tp = (const float*)d_in[8];
  const float* b_tp = (const float*)d_in[9];
  const float* w_te = (const float*)d_in[10];
  const float* ln1g = (const float*)d_in[11];
  const float* ln1b = (const float*)d_in[12];
  const float* wq   = (const float*)d_in[13];
  const float* bq   = (const float*)d_in[14];
  const float* wk   = (const float*)d_in[15];
  const float* bk   = (const float*)d_in[16];
  const float* wv   = (const float*)d_in[17];
  const float* bv   = (const float*)d_in[18];
  const float* wo   = (const float*)d_in[19];
  const float* bo   = (const float*)d_in[20];
  const float* ln2g = (const float*)d_in[21];
  const float* ln2b = (const float*)d_in[22];
  const float* w1   = (const float*)d_in[23];
  const float* b1   = (const float*)d_in[24];
  const float* w2   = (const float*)d_in[25];
  const float* b2   = (const float*)d_in[26];
  const float* nog  = (const float*)d_in[27];
  const float* nob  = (const float*)d_in[28];
  const float* wout = (const float*)d_in[29];
  const float* bout = (const float*)d_in[30];
  const float* rw   = (const float*)d_in[31];
  float* out = (float*)d_out;

  char* p = (char*)d_ws;
  auto alloc = [&](size_t bytes) -> char* {
    char* r = p; p += (bytes + 255) & ~(size_t)255; return r;
  };
  __bf16* wqkvt = (__bf16*)alloc((size_t)NL * 1536 * 512 * 2);
  __bf16* wot_  = (__bf16*)alloc((size_t)NL * 512 * 512 * 2);
  __bf16* w1t   = (__bf16*)alloc((size_t)NL * 512 * 2048 * 2);
  __bf16* w2t   = (__bf16*)alloc((size_t)NL * 512 * 2048 * 2);
  __bf16* wtpt  = (__bf16*)alloc((size_t)512 * 256 * 2);
  __bf16* woutt = (__bf16*)alloc((size_t)256 * 512 * 2);
  float*  bqkv  = (float*)alloc((size_t)NL * 1536 * 4);
  __bf16* zbf   = (__bf16*)alloc((size_t)PROWS * LD * 2);
  float*  x     = (float*)alloc((size_t)ROWS * HD * 4);
  __bf16* y     = (__bf16*)alloc((size_t)ROWS * HD * 2);
  __bf16* qkb   = (__bf16*)alloc((size_t)ROWS * 1024 * 2);
  __bf16* vtb   = (__bf16*)alloc((size_t)ROWS * HD * 2);
  __bf16* ob    = (__bf16*)alloc((size_t)ROWS * HD * 2);
  __bf16* mid   = (__bf16*)alloc((size_t)ROWS * MLPD * 2);
  float*  ptb   = (float*)alloc((size_t)PROWS * HD * 4);
  (void)in_sizes; (void)n_in; (void)out_size; (void)ws_size;

  dim3 tb(32, 8);
  transpose_cast<<<dim3(16, 16, 6), tb, 0, stream>>>(wq, wqkvt,          512,  512,  262144, 786432);
  transpose_cast<<<dim3(16, 16, 6), tb, 0, stream>>>(wk, wqkvt + 262144, 512,  512,  262144, 786432);
  transpose_cast<<<dim3(16, 16, 6), tb, 0, stream>>>(wv, wqkvt + 524288, 512,  512,  262144, 786432);
  transpose_cast<<<dim3(16, 16, 6), tb, 0, stream>>>(wo, wot_,           512,  512,  262144, 262144);
  transpose_cast<<<dim3(64, 16, 6), tb, 0, stream>>>(w1, w1t,            512,  2048, 1048576, 1048576);
  transpose_cast<<<dim3(16, 64, 6), tb, 0, stream>>>(w2, w2t,            2048, 512,  1048576, 1048576);
  transpose_cast<<<dim3(16, 8, 1),  tb, 0, stream>>>(w_tp, wtpt,         256,  512,  0, 0);
  transpose_cast<<<dim3(8, 16, 1),  tb, 0, stream>>>(wout, woutt,        512,  256,  0, 0);
  build_bqkv<<<36, 256, 0, stream>>>(bq, bk, bv, bqkv);
  cast_bf16<<<(PROWS * LD) / 2048, 256, 0, stream>>>(z, zbf);

  gemm_n64<8><<<dim3(8, PROWS / 64), 256, 0, stream>>>(zbf, wtpt, b_tp, nullptr, ptb, nullptr,
                                                       PROWS, 512, 256, nullptr, nullptr);
  act_embed<<<dim3(16, 8), 64, 0, stream>>>(cont, disc, w_de, w_cp, b_cp, w_ap, b_ap, w_te, x);
  assemble_patch<<<(PROWS * HD) / 1024, 256, 0, stream>>>(ptb, w_te, x);

  for (int L = 0; L < NL; ++L) {
    ln_bf16<<<ROWS / 4, 256, 0, stream>>>(x, ln1g + L*HD, ln1b + L*HD, y);
    gemm_w64<32><<<dim3(6, ROWS / 64), 256, 0, stream>>>(y, wqkvt + (size_t)L*786432,
                                                         bqkv + L*1536, nullptr, qkb, vtb,
                                                         ROWS, 1536, 512);
    attn_fwd<<<2112, 256, 0, stream>>>(qkb, vtb, ob);
    gemm_n64<10><<<dim3(8, ROWS / 64), 256, 0, stream>>>(ob, wot_ + (size_t)L*262144, bo + L*HD,
                                                         x, x, nullptr, ROWS, 512, 512,
                                                         nullptr, nullptr);
    ln_bf16<<<ROWS / 4, 256, 0, stream>>>(x, ln2g + L*HD, ln2b + L*HD, y);
    gemm_w64<5><<<dim3(8, ROWS / 64), 256, 0, stream>>>(y, w1t + (size_t)L*1048576, b1 + L*MLPD,
                                                        nullptr, mid, nullptr, ROWS, 2048, 512);
    gemm_n64<10><<<dim3(8, ROWS / 64), 256, 0, stream>>>(mid, w2t + (size_t)L*1048576, b2 + L*HD,
                                                         x, x, nullptr, ROWS, 512, 2048,
                                                         nullptr, nullptr);
  }
  ln_bf16<<<ROWS / 4, 256, 0, stream>>>(x, nog, nob, y);
  gemm_n64<64><<<dim3(4, ROWS / 64), 256, 0, stream>>>(y, woutt, bout, nullptr, out, nullptr,
                                                       ROWS, 256, 512, z, rw);
}

// Round 16
// 1037.287 us; speedup vs baseline: 1.0789x; 1.0789x over previous
//
#include <hip/hip_runtime.h>
#include <hip/hip_bf16.h>
#include <cmath>

typedef __attribute__((ext_vector_type(8)))  __bf16 bf16x8;
typedef __attribute__((ext_vector_type(4)))  float  f32x4;
typedef __attribute__((ext_vector_type(16))) float  f32x16;
typedef const __attribute__((address_space(1))) void* as1cv;
typedef __attribute__((address_space(3))) void*       as3v;

static constexpr int BB = 8, TT = 16, NN = 65, LD = 256, HD = 512, NH = 8, NL = 6;
static constexpr int SS    = TT * (NN + 1);   // 1056
static constexpr int ROWS  = BB * SS;         // 8448
static constexpr int PROWS = BB * TT * NN;    // 8320
static constexpr int MLPD  = 2048;

// ---------- transpose + cast: f32 (R,C) -> bf16 (C,R), batched ----------
__global__ void transpose_cast(const float* __restrict__ in, __bf16* __restrict__ out,
                               int R, int C, size_t ibs, size_t obs)
{
  __shared__ float t[32][33];
  in  += ibs * blockIdx.z;
  out += obs * blockIdx.z;
  int bx = blockIdx.x * 32, by = blockIdx.y * 32;
  #pragma unroll
  for (int i = threadIdx.y; i < 32; i += 8)
    t[i][threadIdx.x] = in[(size_t)(by + i) * C + bx + threadIdx.x];
  __syncthreads();
  #pragma unroll
  for (int i = threadIdx.y; i < 32; i += 8)
    out[(size_t)(bx + i) * R + by + threadIdx.x] = (__bf16)t[threadIdx.x][i];
}

// ---------- straight f32 -> bf16 cast (8 elems/thread) ----------
__global__ __launch_bounds__(256) void cast_bf16(const float* __restrict__ in,
                                                 __bf16* __restrict__ out)
{
  int i = (blockIdx.x * 256 + threadIdx.x) * 8;
  float4 a = *(const float4*)(in + i);
  float4 b = *(const float4*)(in + i + 4);
  bf16x8 o;
  o[0]=(__bf16)a.x; o[1]=(__bf16)a.y; o[2]=(__bf16)a.z; o[3]=(__bf16)a.w;
  o[4]=(__bf16)b.x; o[5]=(__bf16)b.y; o[6]=(__bf16)b.z; o[7]=(__bf16)b.w;
  *(bf16x8*)(out + i) = o;
}

// ---------- concat q/k/v biases into (NL,1536) ----------
__global__ void build_bqkv(const float* __restrict__ bq, const float* __restrict__ bk,
                           const float* __restrict__ bv, float* __restrict__ out)
{
  int i = blockIdx.x * 256 + threadIdx.x;      // 0..9215
  int L = i / 1536, c = i % 1536;
  float v = (c < 512) ? bq[L*512 + c] : (c < 1024 ? bk[L*512 + c - 512] : bv[L*512 + c - 1024]);
  out[i] = v;
}

// ---------- GEMM: BM=64 x BN=128, T1 XCD swizzle (QKV / MLP-up) ----------
// FLAGS: 1=GELU  2=+resid(f32)  4=bf16 out  8=f32 out  32=QKV split (qk normal, v transposed)
template<int FLAGS>
__global__ __launch_bounds__(256)
void gemm_bt(const __bf16* __restrict__ A, const __bf16* __restrict__ Bt,
             const float* __restrict__ bias, const float* __restrict__ resid,
             float* __restrict__ outF, __bf16* __restrict__ outB, __bf16* __restrict__ outB2,
             int M, int N, int K)
{
  __shared__ __bf16 As[64 * 64];
  __shared__ __bf16 Bs[128 * 64];
  const int tid = threadIdx.x;
  const int lane = tid & 63, w = tid >> 6;
  const int g = lane >> 4, cl = lane & 15;
  const int wr = w >> 1, wc = w & 1;
  const int gx = gridDim.x, nwg = gx * gridDim.y;
  const int orig = blockIdx.y * gx + blockIdx.x;
  const int q8 = nwg >> 3, r8 = nwg & 7;
  const int xcd = orig & 7, off = orig >> 3;
  const int tile = (xcd < r8 ? xcd * (q8 + 1) : r8 * (q8 + 1) + (xcd - r8) * q8) + off;
  const int tm = (tile / gx) * 64, tn = (tile % gx) * 128;

  f32x4 acc[2][4];
  const f32x4 zero4 = {0.f, 0.f, 0.f, 0.f};
  #pragma unroll
  for (int m = 0; m < 2; m++)
    #pragma unroll
    for (int n = 0; n < 4; n++) acc[m][n] = zero4;

  const int nk = K >> 6;
  for (int kt = 0; kt < nk; ++kt) {
    __syncthreads();
    const __bf16* Ag = A  + (size_t)tm * K + kt * 64;
    const __bf16* Bg = Bt + (size_t)tn * K + kt * 64;
    #pragma unroll
    for (int p = 0; p < 2; p++) {
      int c = p * 256 + tid;
      int row = c >> 3, j = c & 7;
      int jj = j ^ (row & 7);
      const __bf16* sa = Ag + (size_t)row * K + jj * 8;
      __builtin_amdgcn_global_load_lds((as1cv)sa, (as3v)&As[(p * 4 + w) * 512], 16, 0, 0);
    }
    #pragma unroll
    for (int p = 0; p < 4; p++) {
      int c = p * 256 + tid;
      int row = c >> 3, j = c & 7;
      int jj = j ^ (row & 7);
      const __bf16* sb = Bg + (size_t)row * K + jj * 8;
      __builtin_amdgcn_global_load_lds((as1cv)sb, (as3v)&Bs[(p * 4 + w) * 512], 16, 0, 0);
    }
    __syncthreads();
    #pragma unroll
    for (int kk = 0; kk < 2; kk++) {
      bf16x8 af[2], bfr[4];
      #pragma unroll
      for (int m = 0; m < 2; m++) {
        int row = wr * 32 + m * 16 + cl;
        af[m] = *(const bf16x8*)&As[row * 64 + ((kk * 4 + g) ^ (row & 7)) * 8];
      }
      #pragma unroll
      for (int n = 0; n < 4; n++) {
        int row = wc * 64 + n * 16 + cl;
        bfr[n] = *(const bf16x8*)&Bs[row * 64 + ((kk * 4 + g) ^ (row & 7)) * 8];
      }
      #pragma unroll
      for (int m = 0; m < 2; m++)
        #pragma unroll
        for (int n = 0; n < 4; n++)
          acc[m][n] = __builtin_amdgcn_mfma_f32_16x16x32_bf16(af[m], bfr[n], acc[m][n], 0, 0, 0);
    }
  }
  float bv[4];
  #pragma unroll
  for (int n = 0; n < 4; n++) bv[n] = bias[tn + wc * 64 + n * 16 + cl];
  #pragma unroll
  for (int m = 0; m < 2; m++) {
    int Rb = tm + wr * 32 + m * 16 + g * 4;
    #pragma unroll
    for (int i = 0; i < 4; i++) {
      int R = Rb + i;
      #pragma unroll
      for (int n = 0; n < 4; n++) {
        int C = tn + wc * 64 + n * 16 + cl;
        float v = acc[m][n][i] + bv[n];
        if (FLAGS & 1) v = 0.5f * v * (1.f + erff(v * 0.70710678118f));
        if (FLAGS & 2) v += resid[(size_t)R * N + C];
        if (FLAGS & 8) outF[(size_t)R * N + C] = v;
        if (FLAGS & 4) outB[(size_t)R * N + C] = (__bf16)v;
        if (FLAGS & 32) {
          if (C < 1024) {
            outB[(size_t)R * 1024 + C] = (__bf16)v;           // q|k packed, stride 1024
          } else {
            int bb2 = R / SS, s2 = R % SS;
            int cc = C - 1024, hh = cc >> 6, dd = cc & 63;
            outB2[((size_t)((bb2 * NH + hh) * 64 + dd)) * SS + s2] = (__bf16)v;  // V^T
          }
        }
      }
    }
  }
}

// ---------- GEMM: BM=64 x BN=64 (occupancy-max, small-N GEMMs) ----------
// FLAGS: 1=GELU 2=+resid 4=bf16 8=f32 64=fused final add (out = z + sigmoid(rw)*v, patch scatter)
template<int FLAGS>
__global__ __launch_bounds__(256)
void gemm_n64(const __bf16* __restrict__ A, const __bf16* __restrict__ Bt,
              const float* __restrict__ bias, const float* __restrict__ resid,
              float* __restrict__ outF, __bf16* __restrict__ outB,
              int M, int N, int K,
              const float* __restrict__ zf, const float* __restrict__ rwp)
{
  __shared__ __bf16 As[64 * 64];
  __shared__ __bf16 Bs[64 * 64];
  const int tid = threadIdx.x;
  const int lane = tid & 63, w = tid >> 6;
  const int g = lane >> 4, cl = lane & 15;
  const int wr = w >> 1, wc = w & 1;
  const int gx = gridDim.x, nwg = gx * gridDim.y;
  const int orig = blockIdx.y * gx + blockIdx.x;
  const int q8 = nwg >> 3, r8 = nwg & 7;
  const int xcd = orig & 7, off = orig >> 3;
  const int tile = (xcd < r8 ? xcd * (q8 + 1) : r8 * (q8 + 1) + (xcd - r8) * q8) + off;
  const int tm = (tile / gx) * 64, tn = (tile % gx) * 64;

  f32x4 acc[2][2];
  const f32x4 zero4 = {0.f, 0.f, 0.f, 0.f};
  #pragma unroll
  for (int m = 0; m < 2; m++)
    #pragma unroll
    for (int n = 0; n < 2; n++) acc[m][n] = zero4;

  const int nk = K >> 6;
  for (int kt = 0; kt < nk; ++kt) {
    __syncthreads();
    const __bf16* Ag = A  + (size_t)tm * K + kt * 64;
    const __bf16* Bg = Bt + (size_t)tn * K + kt * 64;
    #pragma unroll
    for (int p = 0; p < 2; p++) {
      int c = p * 256 + tid;
      int row = c >> 3, j = c & 7;
      int jj = j ^ (row & 7);
      const __bf16* sa = Ag + (size_t)row * K + jj * 8;
      const __bf16* sb = Bg + (size_t)row * K + jj * 8;
      __builtin_amdgcn_global_load_lds((as1cv)sa, (as3v)&As[(p * 4 + w) * 512], 16, 0, 0);
      __builtin_amdgcn_global_load_lds((as1cv)sb, (as3v)&Bs[(p * 4 + w) * 512], 16, 0, 0);
    }
    __syncthreads();
    #pragma unroll
    for (int kk = 0; kk < 2; kk++) {
      bf16x8 af[2], bfr[2];
      #pragma unroll
      for (int m = 0; m < 2; m++) {
        int row = wr * 32 + m * 16 + cl;
        af[m] = *(const bf16x8*)&As[row * 64 + ((kk * 4 + g) ^ (row & 7)) * 8];
      }
      #pragma unroll
      for (int n = 0; n < 2; n++) {
        int row = wc * 32 + n * 16 + cl;
        bfr[n] = *(const bf16x8*)&Bs[row * 64 + ((kk * 4 + g) ^ (row & 7)) * 8];
      }
      #pragma unroll
      for (int m = 0; m < 2; m++)
        #pragma unroll
        for (int n = 0; n < 2; n++)
          acc[m][n] = __builtin_amdgcn_mfma_f32_16x16x32_bf16(af[m], bfr[n], acc[m][n], 0, 0, 0);
    }
  }
  const float alphaF = (FLAGS & 64) ? 1.f / (1.f + __expf(-rwp[0])) : 0.f;
  float bv[2];
  #pragma unroll
  for (int n = 0; n < 2; n++) bv[n] = bias[tn + wc * 32 + n * 16 + cl];
  #pragma unroll
  for (int m = 0; m < 2; m++) {
    int Rb = tm + wr * 32 + m * 16 + g * 4;
    #pragma unroll
    for (int i = 0; i < 4; i++) {
      int R = Rb + i;
      #pragma unroll
      for (int n = 0; n < 2; n++) {
        int C = tn + wc * 32 + n * 16 + cl;
        float v = acc[m][n][i] + bv[n];
        if (FLAGS & 1) v = 0.5f * v * (1.f + erff(v * 0.70710678118f));
        if (FLAGS & 2) v += resid[(size_t)R * N + C];
        if (FLAGS & 8) outF[(size_t)R * N + C] = v;
        if (FLAGS & 4) outB[(size_t)R * N + C] = (__bf16)v;
        if (FLAGS & 64) {
          int bb2 = R / SS, s2 = R % SS;
          int t = s2 / 66, k = s2 % 66;
          if (k > 0) {
            size_t oi = ((size_t)((bb2 * TT + t) * NN + (k - 1))) * LD + C;
            outF[oi] = zf[oi] + alphaF * v;
          }
        }
      }
    }
  }
}

// ---------- LayerNorm: f32 in -> bf16 out, 1 wave per 512-col row ----------
__global__ __launch_bounds__(256) void ln_bf16(const float* __restrict__ in,
    const float* __restrict__ gam, const float* __restrict__ bet, __bf16* __restrict__ out)
{
  int w = threadIdx.x >> 6, l = threadIdx.x & 63;
  size_t row = (size_t)blockIdx.x * 4 + w;
  const float4* x4 = (const float4*)(in + row * HD);
  float4 v0 = x4[l], v1 = x4[l + 64];
  float s  = v0.x + v0.y + v0.z + v0.w + v1.x + v1.y + v1.z + v1.w;
  float q2 = v0.x*v0.x + v0.y*v0.y + v0.z*v0.z + v0.w*v0.w
           + v1.x*v1.x + v1.y*v1.y + v1.z*v1.z + v1.w*v1.w;
  #pragma unroll
  for (int m = 1; m < 64; m <<= 1) { s += __shfl_xor(s, m); q2 += __shfl_xor(q2, m); }
  float mean = s * (1.f / HD);
  float rstd = rsqrtf(q2 * (1.f / HD) - mean * mean + 1e-5f);
  int c0 = l * 4, c1 = 256 + l * 4;
  float4 g0 = *(const float4*)(gam + c0), g1 = *(const float4*)(gam + c1);
  float4 e0 = *(const float4*)(bet + c0), e1 = *(const float4*)(bet + c1);
  __bf16* o = out + row * HD;
  o[c0+0] = (__bf16)((v0.x-mean)*rstd*g0.x + e0.x);
  o[c0+1] = (__bf16)((v0.y-mean)*rstd*g0.y + e0.y);
  o[c0+2] = (__bf16)((v0.z-mean)*rstd*g0.z + e0.z);
  o[c0+3] = (__bf16)((v0.w-mean)*rstd*g0.w + e0.w);
  o[c1+0] = (__bf16)((v1.x-mean)*rstd*g1.x + e1.x);
  o[c1+1] = (__bf16)((v1.y-mean)*rstd*g1.y + e1.y);
  o[c1+2] = (__bf16)((v1.z-mean)*rstd*g1.z + e1.z);
  o[c1+3] = (__bf16)((v1.w-mean)*rstd*g1.w + e1.w);
}

// ---------- action-token embedding ----------
__global__ __launch_bounds__(64) void act_embed(const float* __restrict__ cont,
    const int* __restrict__ disc, const float* __restrict__ w_de,
    const float* __restrict__ w_cp, const float* __restrict__ b_cp,
    const float* __restrict__ w_ap, const float* __restrict__ b_ap,
    const float* __restrict__ w_te, float* __restrict__ x)
{
  int t = blockIdx.x, b = blockIdx.y, l = threadIdx.x;
  int da = disc[b * TT + t];
  float c0 = cont[(b * TT + t) * 2], c1 = cont[(b * TT + t) * 2 + 1];
  int c = l * 8;
  float accv[8];
  #pragma unroll
  for (int j = 0; j < 8; j++) accv[j] = b_ap[c + j];
  for (int i = 0; i < 64; i++) {
    float ai = w_de[da * 64 + i];
    #pragma unroll
    for (int j = 0; j < 8; j++) accv[j] += ai * w_ap[i * HD + c + j];
  }
  for (int i = 0; i < 64; i++) {
    float ce = c0 * w_cp[i] + c1 * w_cp[64 + i] + b_cp[i];
    #pragma unroll
    for (int j = 0; j < 8; j++) accv[j] += ce * w_ap[(64 + i) * HD + c + j];
  }
  #pragma unroll
  for (int j = 0; j < 8; j++)
    x[((size_t)(b * SS) + t * 66) * HD + c + j] = accv[j] + w_te[t * HD + c + j];
}

// ---------- scatter patch tokens ----------
__global__ __launch_bounds__(256) void assemble_patch(const float* __restrict__ pt,
    const float* __restrict__ te, float* __restrict__ x)
{
  int idx = (blockIdx.x * 256 + threadIdx.x) * 4;
  int c = idx & (HD - 1);
  int r = idx >> 9;
  int n = r % NN; int bt = r / NN; int t = bt & (TT - 1); int bb = bt >> 4;
  float4 v  = *(const float4*)(pt + idx);
  float4 tv = *(const float4*)(te + t * HD + c);
  v.x += tv.x; v.y += tv.y; v.z += tv.z; v.w += tv.w;
  *(float4*)(x + ((size_t)(bb * SS + t * 66 + 1 + n)) * HD + c) = v;
}

__device__ inline unsigned pkbf(float lo, float hi2) {
  unsigned short a = __builtin_bit_cast(unsigned short, (__bf16)lo);
  unsigned short b = __builtin_bit_cast(unsigned short, (__bf16)hi2);
  return (unsigned)a | ((unsigned)b << 16);
}

// ---------- flash attention v9: split-K + exp2-domain softmax + padded merge ----------
// Block = one (qt,h,b) job; wave w does kv-tiles {w, w+4, ...}; exact exp2 merge.
// XCD-batch grid: XCD x owns batch b=x (K/V L2-resident).
__global__ __launch_bounds__(256) void attn_fwd(const __bf16* __restrict__ qk,
    const __bf16* __restrict__ vT, __bf16* __restrict__ o)
{
  const int w = threadIdx.x >> 6, lane = threadIdx.x & 63;
  const int lin = (blockIdx.x & 7) * 264 + (blockIdx.x >> 3);  // bijective, 2112 blocks
  const int b   = lin / 264;                                   // == blockIdx.x & 7 (XCD)
  const int rem = lin % 264;
  const int h = rem / 33, qt = rem % 33;
  const int l31 = lane & 31, hi = lane >> 5;
  const int q = qt * 32 + l31;
  const int kend = (q / 66 + 1) * 66;
  const int nkv = (((qt * 32 + 31) / 66 + 1) * 66 + 31) >> 5;
  const float SCL = 0.125f * 1.44269504f;    // log2e folded (exp2 domain)

  __shared__ float red[4][32];
  __shared__ float lmS[4][32], llS[4][32];
  __shared__ float laS[3][64][33];           // +1 pad: conflict-free merge
  __shared__ float red2[32][9];              // +1 pad

  bf16x8 qf[4];
  const __bf16* qbase = qk + (size_t)(b * SS + q) * 1024 + h * 64 + hi * 8;
  #pragma unroll
  for (int s = 0; s < 4; s++) qf[s] = *(const bf16x8*)(qbase + s * 16);

  const f32x16 z16 = {0,0,0,0,0,0,0,0,0,0,0,0,0,0,0,0};
  f32x16 accA = z16, accB = z16;
  float m = -1e30f, lsum = 0.f;

  for (int kb = w; kb < nkv; kb += 4) {
    const int K0 = kb * 32;
    const __bf16* kbase = qk + (size_t)(b * SS + K0 + l31) * 1024 + 512 + h * 64 + hi * 8;
    bf16x8 kf0 = *(const bf16x8*)(kbase);
    bf16x8 kf1 = *(const bf16x8*)(kbase + 16);
    bf16x8 kf2 = *(const bf16x8*)(kbase + 32);
    bf16x8 kf3 = *(const bf16x8*)(kbase + 48);
    const __bf16* vbase = vT + (size_t)((b * NH + h) * 64 + l31) * SS + K0 + hi * 8;
    bf16x8 vf00 = *(const bf16x8*)(vbase);
    bf16x8 vf10 = *(const bf16x8*)(vbase + 16);
    bf16x8 vf01 = *(const bf16x8*)(vbase + (size_t)32 * SS);
    bf16x8 vf11 = *(const bf16x8*)(vbase + (size_t)32 * SS + 16);

    f32x16 st = z16;
    st = __builtin_amdgcn_mfma_f32_32x32x16_bf16(kf0, qf[0], st, 0, 0, 0);
    st = __builtin_amdgcn_mfma_f32_32x32x16_bf16(kf1, qf[1], st, 0, 0, 0);
    st = __builtin_amdgcn_mfma_f32_32x32x16_bf16(kf2, qf[2], st, 0, 0, 0);
    st = __builtin_amdgcn_mfma_f32_32x32x16_bf16(kf3, qf[3], st, 0, 0, 0);

    float p[16];
    #pragma unroll
    for (int r = 0; r < 16; r++) {
      int kg = K0 + (r & 3) + 8 * (r >> 2) + 4 * hi;
      p[r] = (kg < kend) ? st[r] * SCL : -1e30f;
    }
    float mx = fmaxf(fmaxf(fmaxf(p[0],p[1]),fmaxf(p[2],p[3])),
                     fmaxf(fmaxf(p[4],p[5]),fmaxf(p[6],p[7])));
    mx = fmaxf(mx, fmaxf(fmaxf(fmaxf(p[8],p[9]),fmaxf(p[10],p[11])),
                         fmaxf(fmaxf(p[12],p[13]),fmaxf(p[14],p[15]))));
    mx = fmaxf(mx, __shfl_xor(mx, 32));
    if (__any(mx > m + 11.5416f)) {          // defer-max, e^8 bound (log2)
      float nm = fmaxf(m, mx);
      float alp = exp2f(m - nm);
      m = nm; lsum *= alp;
      if (lane < 32) red[w][lane] = alp;
      asm volatile("s_waitcnt lgkmcnt(0)" ::: "memory");
      float4 a0 = *(const float4*)&red[w][hi * 4];
      float4 a1 = *(const float4*)&red[w][hi * 4 + 8];
      float4 a2 = *(const float4*)&red[w][hi * 4 + 16];
      float4 a3 = *(const float4*)&red[w][hi * 4 + 24];
      float afv[16] = {a0.x,a0.y,a0.z,a0.w, a1.x,a1.y,a1.z,a1.w,
                       a2.x,a2.y,a2.z,a2.w, a3.x,a3.y,a3.z,a3.w};
      #pragma unroll
      for (int r = 0; r < 16; r++) { accA[r] *= afv[r]; accB[r] *= afv[r]; }
    }
    float rs;
    #pragma unroll
    for (int r = 0; r < 16; r++) p[r] = exp2f(p[r] - m);
    rs = ((p[0]+p[1])+(p[2]+p[3])) + ((p[4]+p[5])+(p[6]+p[7]))
       + ((p[8]+p[9])+(p[10]+p[11])) + ((p[12]+p[13])+(p[14]+p[15]));
    rs += __shfl_xor(rs, 32);
    lsum += rs;
    unsigned a0p = pkbf(p[0], p[1]),  a1p = pkbf(p[2], p[3]);
    unsigned a2p = pkbf(p[4], p[5]),  a3p = pkbf(p[6], p[7]);
    unsigned b0p = pkbf(p[8], p[9]),  b1p = pkbf(p[10], p[11]);
    unsigned b2p = pkbf(p[12], p[13]), b3p = pkbf(p[14], p[15]);
    unsigned s0 = __shfl_xor(a0p, 32), s1 = __shfl_xor(a1p, 32);
    unsigned s2 = __shfl_xor(a2p, 32), s3 = __shfl_xor(a3p, 32);
    unsigned t0 = __shfl_xor(b0p, 32), t1 = __shfl_xor(b1p, 32);
    unsigned t2 = __shfl_xor(b2p, 32), t3 = __shfl_xor(b3p, 32);
    union { unsigned u[4]; bf16x8 v; } af0, af1;
    af0.u[0] = hi ? s2 : a0p;  af0.u[1] = hi ? s3 : a1p;
    af0.u[2] = hi ? a2p : s0;  af0.u[3] = hi ? a3p : s1;
    af1.u[0] = hi ? t2 : b0p;  af1.u[1] = hi ? t3 : b1p;
    af1.u[2] = hi ? b2p : t0;  af1.u[3] = hi ? b3p : t1;
    accA = __builtin_amdgcn_mfma_f32_32x32x16_bf16(af0.v, vf00, accA, 0, 0, 0);
    accA = __builtin_amdgcn_mfma_f32_32x32x16_bf16(af1.v, vf10, accA, 0, 0, 0);
    accB = __builtin_amdgcn_mfma_f32_32x32x16_bf16(af0.v, vf01, accB, 0, 0, 0);
    accB = __builtin_amdgcn_mfma_f32_32x32x16_bf16(af1.v, vf11, accB, 0, 0, 0);
  }

  // ---- split-K merge: O = sum_w O_w 2^{m_w-M}; L = sum_w l_w 2^{m_w-M} ----
  if (lane < 32) { lmS[w][lane] = m; llS[w][lane] = lsum; }
  if (w > 0) {
    #pragma unroll
    for (int r = 0; r < 16; r++) {
      laS[w - 1][lane][r]      = accA[r];
      laS[w - 1][lane][16 + r] = accB[r];
    }
  }
  __syncthreads();
  if (w != 0) return;
  float m0 = lmS[0][l31], m1 = lmS[1][l31], m2 = lmS[2][l31], m3 = lmS[3][l31];
  float M = fmaxf(fmaxf(m0, m1), fmaxf(m2, m3));
  float f0 = exp2f(m0 - M), f1 = exp2f(m1 - M);
  float f2 = exp2f(m2 - M), f3 = exp2f(m3 - M);
  float L = llS[0][l31] * f0 + llS[1][l31] * f1 + llS[2][l31] * f2 + llS[3][l31] * f3;
  if (lane < 32) {
    red2[lane][0] = f0; red2[lane][1] = f1;
    red2[lane][2] = f2; red2[lane][3] = f3;
    red2[lane][4] = 1.f / L;
  }
  asm volatile("s_waitcnt lgkmcnt(0)" ::: "memory");
  __bf16* obase = o + (size_t)(b * SS + qt * 32) * HD + h * 64 + l31;
  #pragma unroll
  for (int r = 0; r < 16; r++) {
    int qr = (r & 3) + 8 * (r >> 2) + 4 * hi;
    float4 fv = *(const float4*)&red2[qr][0];
    float il = red2[qr][4];
    float oa = (accA[r] * fv.x + laS[0][lane][r] * fv.y
              + laS[1][lane][r] * fv.z + laS[2][lane][r] * fv.w) * il;
    float ob = (accB[r] * fv.x + laS[0][lane][16 + r] * fv.y
              + laS[1][lane][16 + r] * fv.z + laS[2][lane][16 + r] * fv.w) * il;
    obase[(size_t)qr * HD]      = (__bf16)oa;
    obase[(size_t)qr * HD + 32] = (__bf16)ob;
  }
}

extern "C" void kernel_launch(void* const* d_in, const int* in_sizes, int n_in,
                              void* d_out, int out_size, void* d_ws, size_t ws_size,
                              hipStream_t stream)
{
  const float* z    = (const float*)d_in[0];
  const float* cont = (const float*)d_in[1];
  const int*   disc = (const int*)d_in[2];
  const float* w_de = (const float*)d_in[3];
  const float* w_cp = (const float*)d_in[4];
  const float* b_cp = (const float*)d_in[5];
  const float* w_ap = (const float*)d_in[6];
  const float* b_ap = (const float*)d_in[7];
  const float* w_tp = (const float*)d_in[8];
  const float* b_tp = (const float*)d_in[9];
  const float* w_te = (const float*)d_in[10];
  const float* ln1g = (const float*)d_in[11];
  const float* ln1b = (const float*)d_in[12];
  const float* wq   = (const float*)d_in[13];
  const float* bq   = (const float*)d_in[14];
  const float* wk   = (const float*)d_in[15];
  const float* bk   = (const float*)d_in[16];
  const float* wv   = (const float*)d_in[17];
  const float* bv   = (const float*)d_in[18];
  const float* wo   = (const float*)d_in[19];
  const float* bo   = (const float*)d_in[20];
  const float* ln2g = (const float*)d_in[21];
  const float* ln2b = (const float*)d_in[22];
  const float* w1   = (const float*)d_in[23];
  const float* b1   = (const float*)d_in[24];
  const float* w2   = (const float*)d_in[25];
  const float* b2   = (const float*)d_in[26];
  const float* nog  = (const float*)d_in[27];
  const float* nob  = (const float*)d_in[28];
  const float* wout = (const float*)d_in[29];
  const float* bout = (const float*)d_in[30];
  const float* rw   = (const float*)d_in[31];
  float* out = (float*)d_out;

  char* p = (char*)d_ws;
  auto alloc = [&](size_t bytes) -> char* {
    char* r = p; p += (bytes + 255) & ~(size_t)255; return r;
  };
  __bf16* wqkvt = (__bf16*)alloc((size_t)NL * 1536 * 512 * 2);
  __bf16* wot_  = (__bf16*)alloc((size_t)NL * 512 * 512 * 2);
  __bf16* w1t   = (__bf16*)alloc((size_t)NL * 512 * 2048 * 2);
  __bf16* w2t   = (__bf16*)alloc((size_t)NL * 512 * 2048 * 2);
  __bf16* wtpt  = (__bf16*)alloc((size_t)512 * 256 * 2);
  __bf16* woutt = (__bf16*)alloc((size_t)256 * 512 * 2);
  float*  bqkv  = (float*)alloc((size_t)NL * 1536 * 4);
  __bf16* zbf   = (__bf16*)alloc((size_t)PROWS * LD * 2);
  float*  x     = (float*)alloc((size_t)ROWS * HD * 4);
  __bf16* y     = (__bf16*)alloc((size_t)ROWS * HD * 2);
  __bf16* qkb   = (__bf16*)alloc((size_t)ROWS * 1024 * 2);
  __bf16* vtb   = (__bf16*)alloc((size_t)ROWS * HD * 2);
  __bf16* ob    = (__bf16*)alloc((size_t)ROWS * HD * 2);
  __bf16* mid   = (__bf16*)alloc((size_t)ROWS * MLPD * 2);
  float*  ptb   = (float*)alloc((size_t)PROWS * HD * 4);
  (void)in_sizes; (void)n_in; (void)out_size; (void)ws_size;

  dim3 tb(32, 8);
  transpose_cast<<<dim3(16, 16, 6), tb, 0, stream>>>(wq, wqkvt,          512,  512,  262144, 786432);
  transpose_cast<<<dim3(16, 16, 6), tb, 0, stream>>>(wk, wqkvt + 262144, 512,  512,  262144, 786432);
  transpose_cast<<<dim3(16, 16, 6), tb, 0, stream>>>(wv, wqkvt + 524288, 512,  512,  262144, 786432);
  transpose_cast<<<dim3(16, 16, 6), tb, 0, stream>>>(wo, wot_,           512,  512,  262144, 262144);
  transpose_cast<<<dim3(64, 16, 6), tb, 0, stream>>>(w1, w1t,            512,  2048, 1048576, 1048576);
  transpose_cast<<<dim3(16, 64, 6), tb, 0, stream>>>(w2, w2t,            2048, 512,  1048576, 1048576);
  transpose_cast<<<dim3(16, 8, 1),  tb, 0, stream>>>(w_tp, wtpt,         256,  512,  0, 0);
  transpose_cast<<<dim3(8, 16, 1),  tb, 0, stream>>>(wout, woutt,        512,  256,  0, 0);
  build_bqkv<<<36, 256, 0, stream>>>(bq, bk, bv, bqkv);
  cast_bf16<<<(PROWS * LD) / 2048, 256, 0, stream>>>(z, zbf);

  gemm_n64<8><<<dim3(8, PROWS / 64), 256, 0, stream>>>(zbf, wtpt, b_tp, nullptr, ptb, nullptr,
                                                       PROWS, 512, 256, nullptr, nullptr);
  act_embed<<<dim3(16, 8), 64, 0, stream>>>(cont, disc, w_de, w_cp, b_cp, w_ap, b_ap, w_te, x);
  assemble_patch<<<(PROWS * HD) / 1024, 256, 0, stream>>>(ptb, w_te, x);

  for (int L = 0; L < NL; ++L) {
    ln_bf16<<<ROWS / 4, 256, 0, stream>>>(x, ln1g + L*HD, ln1b + L*HD, y);
    gemm_bt<32><<<dim3(12, ROWS / 64), 256, 0, stream>>>(y, wqkvt + (size_t)L*786432,
                                                         bqkv + L*1536, nullptr, nullptr,
                                                         qkb, vtb, ROWS, 1536, 512);
    attn_fwd<<<2112, 256, 0, stream>>>(qkb, vtb, ob);
    gemm_n64<10><<<dim3(8, ROWS / 64), 256, 0, stream>>>(ob, wot_ + (size_t)L*262144, bo + L*HD,
                                                         x, x, nullptr, ROWS, 512, 512,
                                                         nullptr, nullptr);
    ln_bf16<<<ROWS / 4, 256, 0, stream>>>(x, ln2g + L*HD, ln2b + L*HD, y);
    gemm_bt<5><<<dim3(16, ROWS / 64), 256, 0, stream>>>(y, w1t + (size_t)L*1048576, b1 + L*MLPD,
                                                        nullptr, nullptr, mid, nullptr,
                                                        ROWS, 2048, 512);
    gemm_n64<10><<<dim3(8, ROWS / 64), 256, 0, stream>>>(mid, w2t + (size_t)L*1048576, b2 + L*HD,
                                                         x, x, nullptr, ROWS, 512, 2048,
                                                         nullptr, nullptr);
  }
  ln_bf16<<<ROWS / 4, 256, 0, stream>>>(x, nog, nob, y);
  gemm_n64<64><<<dim3(4, ROWS / 64), 256, 0, stream>>>(y, woutt, bout, nullptr, out, nullptr,
                                                       ROWS, 256, 512, z, rw);
}